// Round 6
// baseline (857.575 us; speedup 1.0000x reference)
//
#include <hip/hip_runtime.h>
#include <hip/hip_bf16.h>
#include <cstdint>
#include <cstddef>

// H=8 D=256 R=6 S=2 K=2 EV=2, HID=2048, DV=512, b=2, t=1024
typedef __bf16 bf16_t;
typedef __bf16 bf16x8 __attribute__((ext_vector_type(8)));
typedef float f32x4 __attribute__((ext_vector_type(4)));
typedef float f32x16 __attribute__((ext_vector_type(16)));

typedef __attribute__((address_space(3))) unsigned int lds_uint_t;
typedef __attribute__((address_space(1))) unsigned int glob_uint_t;

__device__ __forceinline__ void gload16(const void* g, void* l) {
  __builtin_amdgcn_global_load_lds((const glob_uint_t*)g, (lds_uint_t*)l, 16, 0, 0);
}

__device__ __forceinline__ f32x4 mfma16(bf16x8 a, bf16x8 b, f32x4 c) {
  return __builtin_amdgcn_mfma_f32_16x16x32_bf16(a, b, c, 0, 0, 0);
}
__device__ __forceinline__ f32x16 mfma32(bf16x8 a, bf16x8 b, f32x16 c) {
  return __builtin_amdgcn_mfma_f32_32x32x16_bf16(a, b, c, 0, 0, 0);
}

// ---------------- flat f32 -> bf16 ----------------
__global__ __launch_bounds__(256) void conv_bf16_k(const float* __restrict__ in,
                                                   bf16_t* __restrict__ out, int n8) {
  int i = blockIdx.x * 256 + threadIdx.x;
  if (i >= n8) return;
  f32x4 a = *(const f32x4*)(in + (size_t)i * 8);
  f32x4 b = *(const f32x4*)(in + (size_t)i * 8 + 4);
  bf16x8 o;
  o[0] = (bf16_t)a[0]; o[1] = (bf16_t)a[1]; o[2] = (bf16_t)a[2]; o[3] = (bf16_t)a[3];
  o[4] = (bf16_t)b[0]; o[5] = (bf16_t)b[1]; o[6] = (bf16_t)b[2]; o[7] = (bf16_t)b[3];
  *(bf16x8*)(out + (size_t)i * 8) = o;
}

// ---------------- transpose + convert: in f32 [R][C] -> out bf16 [C][R] ----------------
__global__ __launch_bounds__(256) void tconv_k(const float* __restrict__ in, bf16_t* __restrict__ out,
                                               int R, int C, size_t inZ, size_t outZ) {
  __shared__ __align__(16) bf16_t t[64 * 72];
  in += (size_t)blockIdx.z * inZ;
  out += (size_t)blockIdx.z * outZ;
  const int c0 = blockIdx.x * 64, r0 = blockIdx.y * 64;
  const int tid = threadIdx.x;
#pragma unroll
  for (int it = 0; it < 4; it++) {
    int c = tid + it * 256;           // 1024 chunks of 4 floats (64 rows x 16)
    int row = c >> 4, ch = c & 15;
    f32x4 v = *(const f32x4*)(in + (size_t)(r0 + row) * C + c0 + ch * 4);
#pragma unroll
    for (int j = 0; j < 4; j++) t[(ch * 4 + j) * 72 + row] = (bf16_t)v[j];
  }
  __syncthreads();
#pragma unroll
  for (int it = 0; it < 2; it++) {
    int c = tid + it * 256;           // 512 chunks of 8 bf16 (64 out-rows x 8)
    int oc = c >> 3, ch = c & 7;
    bf16x8 v = *(const bf16x8*)(t + oc * 72 + ch * 8);
    *(bf16x8*)(out + (size_t)(c0 + oc) * R + r0 + ch * 8) = v;
  }
}

// ---------------- transpose V: v bf16 [2048][4096] -> Vt [b][h][512][1024] ----------------
__global__ __launch_bounds__(256) void tv_k(const bf16_t* __restrict__ v, bf16_t* __restrict__ Vt) {
  __shared__ __align__(16) bf16_t t[64 * 72];
  const int tt0 = blockIdx.x * 64;
  const int dv0 = blockIdx.y * 64;
  const int bh = blockIdx.z;
  const int b = bh >> 3, h = bh & 7;
  const int tid = threadIdx.x;
  const bf16_t* src = v + (size_t)(b * 1024 + tt0) * 4096 + h * 512 + dv0;
#pragma unroll
  for (int it = 0; it < 2; it++) {
    int c = tid + it * 256;           // 64 t-rows x 8 chunks
    int row = c >> 3, ch = c & 7;
    bf16x8 x = *(const bf16x8*)(src + (size_t)row * 4096 + ch * 8);
#pragma unroll
    for (int j = 0; j < 8; j++) t[(ch * 8 + j) * 72 + row] = x[j];
  }
  __syncthreads();
  bf16_t* dst = Vt + (size_t)bh * 524288 + (size_t)dv0 * 1024 + tt0;
#pragma unroll
  for (int it = 0; it < 2; it++) {
    int c = tid + it * 256;           // 64 dv-rows x 8 chunks
    int od = c >> 3, ch = c & 7;
    bf16x8 x = *(const bf16x8*)(t + od * 72 + ch * 8);
    *(bf16x8*)(dst + (size_t)od * 1024 + ch * 8) = x;
  }
}

// ---------------- Wfused[kk][h*4+n] = sum_d Wq[kk][h*256+d] * Wgate[d][n] (fp32) ----------------
__global__ __launch_bounds__(256) void wfuse_k(const float* __restrict__ Wq, const float* __restrict__ Wgate,
                                               float* __restrict__ Wf) {
  __shared__ float wg[1024];
  const int tid = threadIdx.x;
  for (int i = tid; i < 1024; i += 256) wg[i] = Wgate[i];
  __syncthreads();
  const int kk = blockIdx.x * 64 + (tid & 63);
  const int oid = tid >> 6;  // 0..3 -> outputs oid*8..+7
  float acc[8] = {0, 0, 0, 0, 0, 0, 0, 0};
  const float* wr = Wq + (size_t)kk * 2048;
#pragma unroll
  for (int half = 0; half < 2; half++) {
    const int h = oid * 2 + half;
    const float* seg = wr + h * 256;
    for (int d = 0; d < 256; d += 4) {
      f32x4 q4 = *(const f32x4*)(seg + d);
#pragma unroll
      for (int n = 0; n < 4; n++) {
        acc[half * 4 + n] += q4[0] * wg[(d + 0) * 4 + n] + q4[1] * wg[(d + 1) * 4 + n] +
                             q4[2] * wg[(d + 2) * 4 + n] + q4[3] * wg[(d + 3) * 4 + n];
      }
    }
  }
#pragma unroll
  for (int jj = 0; jj < 8; jj++) Wf[(size_t)kk * 32 + oid * 8 + jj] = acc[jj];
}

// ---------------- logits[bt][32] = hs[bt] @ Wfused (fp32) ----------------
__global__ __launch_bounds__(256) void logits_k(const float* __restrict__ hs, const float* __restrict__ Wf,
                                                float* __restrict__ lg) {
  __shared__ __align__(16) float hrow[2048];
  __shared__ float red[8][32];
  const int bt = blockIdx.x;
  const int tid = threadIdx.x;
  const float* src = hs + (size_t)bt * 2048;
  for (int i = tid; i < 512; i += 256) *(f32x4*)&hrow[i * 4] = *(const f32x4*)(src + i * 4);
  __syncthreads();
  const int j = tid & 31, part = tid >> 5;
  float acc = 0.f;
  for (int kk = part * 256; kk < part * 256 + 256; kk++) acc += hrow[kk] * Wf[(size_t)kk * 32 + j];
  red[part][j] = acc;
  __syncthreads();
  if (tid < 32) {
    float s = 0.f;
#pragma unroll
    for (int p = 0; p < 8; p++) s += red[p][tid];
    lg[(size_t)bt * 32 + tid] = s;
  }
}

// ---------------- routing: softmax over 4, top-2, weights -> rw[r][b][h][t] (fp32) ----------------
__global__ __launch_bounds__(256) void routing_k(const float* __restrict__ lg, float* __restrict__ rw) {
  int gid = blockIdx.x * 256 + threadIdx.x;
  if (gid >= 16384) return;
  const int h = gid >> 11;
  const int bt = gid & 2047;
  const int b = bt >> 10, tt = bt & 1023;
  f32x4 l = *(const f32x4*)(lg + (size_t)bt * 32 + h * 4);
  float mx = fmaxf(fmaxf(l[0], l[1]), fmaxf(l[2], l[3]));
  float e0 = __expf(l[0] - mx), e1 = __expf(l[1] - mx), e2 = __expf(l[2] - mx), e3 = __expf(l[3] - mx);
  float den = e0 + e1 + e2 + e3;
  float s[4] = {e0 / den, e1 / den, e2 / den, e3 / den};
  int i1 = 0;
#pragma unroll
  for (int i = 1; i < 4; i++) if (s[i] > s[i1]) i1 = i;
  int i2 = (i1 == 0) ? 1 : 0;
#pragma unroll
  for (int i = 0; i < 4; i++) if (i != i1 && s[i] > s[i2]) i2 = i;
  float sw = s[i1] + s[i2];
  float w1 = s[i1] / sw, w2 = s[i2] / sw;
  float tot = 1.0f + w1 + w2;
  float o[6] = {0.5f / tot, 0.5f / tot, 0.f, 0.f, 0.f, 0.f};
  o[2 + i1] = w1 / tot;
  o[2 + i2] = w2 / tot;
#pragma unroll
  for (int r = 0; r < 6; r++) rw[(size_t)((r * 2 + b) * 8 + h) * 1024 + tt] = o[r];
}

// ---------------- bf16 GEMM, 128x128 tile, BK=64, m97-style (A row-major, B stored transposed [N][K]) ----
// MODE 0: C bf16 [M][ldc]; MODE 1: C scattered into qe[r][b][h][t][256] (z = head); MODE 2: C f32.
template <int MODE>
__global__ __launch_bounds__(256) void gemm_bt(const bf16_t* __restrict__ A, const bf16_t* __restrict__ B,
                                               void* __restrict__ Cp, int K, int lda, int ldb, int ldc,
                                               size_t aZ, size_t bZ) {
  __shared__ __align__(16) bf16_t lsA[128 * 64];
  __shared__ __align__(16) bf16_t lsB[128 * 64];
  const int tid = threadIdx.x;
  const int lane = tid & 63, wv = tid >> 6;
  const int lrow = lane & 15, lgrp = lane >> 4;
  const int wr = wv >> 1, wc = wv & 1;
  const int bn = blockIdx.x * 128, bm = blockIdx.y * 128;
  const int z = blockIdx.z;
  A += (size_t)z * aZ;
  B += (size_t)z * bZ;

  f32x4 zero = {0.f, 0.f, 0.f, 0.f};
  f32x4 acc[4][4];
#pragma unroll
  for (int i = 0; i < 4; i++)
#pragma unroll
    for (int j = 0; j < 4; j++) acc[i][j] = zero;

  for (int k0 = 0; k0 < K; k0 += 64) {
    __syncthreads();
#pragma unroll
    for (int it = 0; it < 4; it++) {
      int c = tid + it * 256;
      int row = c >> 3, coff = (c & 7) * 16;
      gload16((const char*)A + ((size_t)(bm + row) * lda + k0) * 2 + coff, (char*)lsA + row * 128 + coff);
      gload16((const char*)B + ((size_t)(bn + row) * ldb + k0) * 2 + coff, (char*)lsB + row * 128 + coff);
    }
    __syncthreads();
#pragma unroll
    for (int kk = 0; kk < 2; kk++) {
      bf16x8 af[4], bfr[4];
#pragma unroll
      for (int m4 = 0; m4 < 4; m4++)
        af[m4] = *(const bf16x8*)((const char*)lsA + (wr * 64 + m4 * 16 + lrow) * 128 + kk * 64 + lgrp * 16);
#pragma unroll
      for (int n4 = 0; n4 < 4; n4++)
        bfr[n4] = *(const bf16x8*)((const char*)lsB + (wc * 64 + n4 * 16 + lrow) * 128 + kk * 64 + lgrp * 16);
#pragma unroll
      for (int m4 = 0; m4 < 4; m4++)
#pragma unroll
        for (int n4 = 0; n4 < 4; n4++) acc[m4][n4] = mfma16(af[m4], bfr[n4], acc[m4][n4]);
    }
  }
#pragma unroll
  for (int m4 = 0; m4 < 4; m4++) {
#pragma unroll
    for (int i = 0; i < 4; i++) {
      const int row = bm + wr * 64 + m4 * 16 + lgrp * 4 + i;
#pragma unroll
      for (int n4 = 0; n4 < 4; n4++) {
        const int col = bn + wc * 64 + n4 * 16 + lrow;
        float v = acc[m4][n4][i];
        if constexpr (MODE == 0) {
          ((bf16_t*)Cp)[(size_t)row * ldc + col] = (bf16_t)v;
        } else if constexpr (MODE == 1) {
          const int bb = row >> 10, tt = row & 1023;
          const int rr = col >> 8, dd = col & 255;
          ((bf16_t*)Cp)[((size_t)((rr * 2 + bb) * 8 + z) * 1024 + tt) * 256 + dd] = (bf16_t)v;
        } else {
          ((float*)Cp)[(size_t)row * ldc + col] = v;
        }
      }
    }
  }
}

// ---------------- fused masked attention, 32x32 MFMA path ----------------
// 256 blocks XCD-swizzled: f = bh*16 + qt*2 + dvh. Block = 4 waves, wave = 32 q-rows x 256 dv.
// LDS-BW optimized: mfma_32x32x16 doubles FLOP per staged byte vs 16x16x32.
// Fixed-M softmax; masked key -> exp(0)=1 in denom, 0 in PV.
__global__ __launch_bounds__(256) void attn_k(const bf16_t* __restrict__ qe, const bf16_t* __restrict__ ke,
                                              const bf16_t* __restrict__ Vt, const float* __restrict__ rw,
                                              const bf16_t* __restrict__ g, bf16_t* __restrict__ oc) {
  __shared__ __align__(16) bf16_t ldsK[2][32 * 256];   // [buf][key][512B row], swz: off ^= (key&7)<<4
  __shared__ __align__(16) bf16_t ldsV[2][256 * 32];   // [buf][dv][64B row],   swz: off ^= ((dv>>1)&3)<<4
  __shared__ __align__(16) bf16_t ldsP[4][32 * 32];    // per-wave P, swz: off ^= v(q)<<4

  const int f = (blockIdx.x & 7) * 32 + (blockIdx.x >> 3);  // bijective XCD swizzle (256 = 8x32)
  const int dvh = f & 1, qt = (f >> 1) & 7, bh = f >> 4;

  const int tid = threadIdx.x;
  const int wv = tid >> 6, lane = tid & 63;
  const int kq = lane & 31, hi = lane >> 5;
  const int b = bh >> 3, h = bh & 7;
  const int qw = qt * 128 + wv * 32;  // wave's q base

  const char* vbase = (const char*)Vt + ((size_t)bh * 524288 + (size_t)dvh * 262144) * 2;

  auto issue_tile = [&](int rr, int kt, int buf) {
    const char* kb = (const char*)ke + ((size_t)((rr * 2 + b) * 8 + h) * 262144 + (size_t)kt * 8192) * 2;
    char* lk = (char*)ldsK[buf];
#pragma unroll
    for (int it = 0; it < 4; it++) {
      int p = (wv * 4 + it) * 1024 + (lane << 4);
      int row = p >> 9, off = p & 511;
      gload16(kb + (size_t)row * 512 + (off ^ ((row & 7) << 4)), lk + p);
    }
    const char* vb = vbase + kt * 64;
    char* lv = (char*)ldsV[buf];
#pragma unroll
    for (int it = 0; it < 4; it++) {
      int p = (wv * 4 + it) * 1024 + (lane << 4);
      int row = p >> 6, off = p & 63;
      gload16(vb + (size_t)row * 2048 + (off ^ (((row >> 1) & 3) << 4)), lv + p);
    }
  };

  f32x16 zero16 = {0.f};
  f32x16 Otot[8];
#pragma unroll
  for (int n = 0; n < 8; n++) Otot[n] = zero16;

  char* pw = (char*)ldsP[wv];
  const int vr = (kq & 3) ^ ((kq >> 2) & 3);  // P read-side swizzle selector

  int cur = 0;
  issue_tile(0, 0, 0);

  for (int r = 0; r < 6; r++) {
    const size_t rbh = (size_t)((r * 2 + b) * 8 + h);
    const bf16_t* qbase = qe + rbh * 262144;
    const float* rwb = rw + rbh * 1024;

    // Q A-frags: row = kq (q), k-elems = hi*8 + i within each 16-d slice
    bf16x8 qf[16];
    {
      const bf16_t* qrow = qbase + (size_t)(qw + kq) * 256 + hi * 8;
#pragma unroll
      for (int s = 0; s < 16; s++) qf[s] = *(const bf16x8*)(qrow + s * 16);
    }

    float Lp[16];
#pragma unroll
    for (int rg = 0; rg < 16; rg++) Lp[rg] = 0.f;
    f32x16 accO[8];
#pragma unroll
    for (int n = 0; n < 8; n++) accO[n] = zero16;

    for (int kt = 0; kt < 32; kt++) {
      asm volatile("s_waitcnt vmcnt(0) lgkmcnt(0)" ::: "memory");
      __syncthreads();
      {
        int nr = r + ((kt == 31) ? 1 : 0);
        int nkt = (kt + 1) & 31;
        if (nr < 6) issue_tile(nr, nkt, cur ^ 1);
      }
      const char* lK = (const char*)ldsK[cur];
      const char* lV = (const char*)ldsV[cur];
      const float mk = rwb[kt * 32 + kq];

      // QK^T: 32q x 32k over d=256, two independent accumulator chains
      f32x16 sA = zero16, sB = zero16;
      __builtin_amdgcn_s_setprio(1);
#pragma unroll
      for (int s = 0; s < 16; s += 2) {
        bf16x8 k0 = *(const bf16x8*)(lK + (size_t)kq * 512 + ((s * 32 + hi * 16) ^ ((kq & 7) << 4)));
        bf16x8 k1 = *(const bf16x8*)(lK + (size_t)kq * 512 + (((s + 1) * 32 + hi * 16) ^ ((kq & 7) << 4)));
        sA = mfma32(qf[s], k0, sA);
        sB = mfma32(qf[s + 1], k1, sB);
      }
      __builtin_amdgcn_s_setprio(0);

      // fixed-M softmax: P = exp(s/16) (0 if masked); denom += exp or 1
      const bool act = (mk != 0.f);
#pragma unroll
      for (int rg = 0; rg < 16; rg++) {
        float e = __expf((sA[rg] + sB[rg]) * 0.0625f);
        Lp[rg] += act ? e : 1.f;
        // q (row) = (rg&3) + 8*(rg>>2) + 4*hi ; write-side swizzle v(q) = (q&3)^((q>>2)&3)
        const int q32 = (rg & 3) + 8 * (rg >> 2) + 4 * hi;
        const int vq = (rg & 3) ^ ((2 * (rg >> 2) + hi) & 3);
        *(bf16_t*)(pw + q32 * 64 + ((kq * 2) ^ (vq << 4))) = (bf16_t)(act ? e : 0.f);
      }

      // PV: A = P (row=q=kq, k = slice*16 + hi*8), B = V (col=dv, same k)
      bf16x8 pa0 = *(const bf16x8*)(pw + kq * 64 + ((hi * 16) ^ (vr << 4)));
      bf16x8 pa1 = *(const bf16x8*)(pw + kq * 64 + ((32 + hi * 16) ^ (vr << 4)));
      __builtin_amdgcn_s_setprio(1);
#pragma unroll
      for (int n = 0; n < 8; n++) {
        const size_t vrow = (size_t)(n * 32 + kq) * 64;
        const int vswz = ((kq >> 1) & 3) << 4;
        bf16x8 v0 = *(const bf16x8*)(lV + vrow + ((hi * 16) ^ vswz));
        bf16x8 v1 = *(const bf16x8*)(lV + vrow + ((32 + hi * 16) ^ vswz));
        accO[n] = mfma32(pa0, v0, accO[n]);
        accO[n] = mfma32(pa1, v1, accO[n]);
      }
      __builtin_amdgcn_s_setprio(0);
      cur ^= 1;
    }  // kt

    // denom reduce across keys (lanes within each 32-half) once per r; weighted accumulate
#pragma unroll
    for (int rg = 0; rg < 16; rg++) {
      float v = Lp[rg];
      v += __shfl_xor(v, 1, 32);
      v += __shfl_xor(v, 2, 32);
      v += __shfl_xor(v, 4, 32);
      v += __shfl_xor(v, 8, 32);
      v += __shfl_xor(v, 16, 32);
      const int q32 = (rg & 3) + 8 * (rg >> 2) + 4 * hi;
      float wq = rwb[qw + q32] / v;
#pragma unroll
      for (int n = 0; n < 8; n++) Otot[n][rg] += accO[n][rg] * wq;
    }
  }  // r

  // epilogue: o * silu(g) -> oc bf16
#pragma unroll
  for (int rg = 0; rg < 16; rg++) {
    const int q32 = (rg & 3) + 8 * (rg >> 2) + 4 * hi;
    const size_t grow = ((size_t)(b * 1024 + qw + q32)) * 8192 + h * 512 + dvh * 256 + kq;
    const size_t orow = ((size_t)(b * 1024 + qw + q32)) * 4096 + h * 512 + dvh * 256 + kq;
#pragma unroll
    for (int n = 0; n < 8; n++) {
      float gv = (float)g[grow + n * 32];
      float sg = gv / (1.f + __expf(-gv));
      oc[orow + n * 32] = (bf16_t)(Otot[n][rg] * sg);
    }
  }
}

// =====================================================================================
extern "C" void kernel_launch(void* const* d_in, const int* in_sizes, int n_in,
                              void* d_out, int out_size, void* d_ws, size_t ws_size,
                              hipStream_t stream) {
  const float* hs  = (const float*)d_in[0];
  const float* Wq  = (const float*)d_in[1];
  const float* Wk  = (const float*)d_in[2];
  const float* Wv  = (const float*)d_in[3];
  const float* Wqe = (const float*)d_in[4];
  const float* Wke = (const float*)d_in[5];
  const float* Wgt = (const float*)d_in[6];
  const float* Wg  = (const float*)d_in[7];
  const float* Wo  = (const float*)d_in[8];
  float* out = (float*)d_out;

  // Liveness-aware workspace layout; peak footprint ~197 MB.
  const size_t MB = 1024 * 1024;
  char* w = (char*)d_ws;
  bf16_t* hs_bf = (bf16_t*)(w + 0 * MB);    // 8MB, dead after projections
  bf16_t* WcatT = (bf16_t*)(w + 8 * MB);    // 32MB: WqT[2048]|WkT[2048]|WgT[4096] rows x 2048
  bf16_t* WvT   = (bf16_t*)(w + 40 * MB);   // 16MB, dead after v proj
  bf16_t* qeB   = (bf16_t*)(w + 0 * MB);    // 48MB, written AFTER all projections (overlays above)
  bf16_t* WoT   = (bf16_t*)(w + 56 * MB);   // 16MB, persistent
  bf16_t* WqeT  = (bf16_t*)(w + 72 * MB);   // 6MB
  bf16_t* WkeT  = (bf16_t*)(w + 78 * MB);   // 6MB
  bf16_t* qkg   = (bf16_t*)(w + 84 * MB);   // 32MB: [2048][8192] = q|k|g merged proj output
  bf16_t* vb    = (bf16_t*)(w + 116 * MB);  // 16MB, dead after tv_k
  bf16_t* ocB   = (bf16_t*)(w + 116 * MB);  // 16MB, written in attn (after tv_k)
  bf16_t* Vt    = (bf16_t*)(w + 132 * MB);  // 16MB
  bf16_t* keB   = (bf16_t*)(w + 148 * MB);  // 48MB
  float*  Wf    = (float*)(w + 196 * MB);             // 256KB
  float*  lg    = (float*)(w + 196 * MB + 262144);    // 256KB
  float*  rwB   = (float*)(w + 196 * MB + 524288);    // 384KB
  (void)ws_size; (void)in_sizes; (void)n_in; (void)out_size;

  // conversions / transposes
  conv_bf16_k<<<2048, 256, 0, stream>>>(hs, hs_bf, 524288);
  tconv_k<<<dim3(32, 32, 1), 256, 0, stream>>>(Wq, WcatT, 2048, 2048, 0, 0);
  tconv_k<<<dim3(32, 32, 1), 256, 0, stream>>>(Wk, WcatT + 2048 * 2048, 2048, 2048, 0, 0);
  tconv_k<<<dim3(64, 32, 1), 256, 0, stream>>>(Wg, WcatT + 4096 * 2048, 2048, 4096, 0, 0);
  tconv_k<<<dim3(64, 32, 1), 256, 0, stream>>>(Wv, WvT, 2048, 4096, 0, 0);
  tconv_k<<<dim3(32, 64, 1), 256, 0, stream>>>(Wo, WoT, 4096, 2048, 0, 0);
  tconv_k<<<dim3(24, 4, 8), 256, 0, stream>>>(Wqe, WqeT, 256, 1536, 393216, 393216);
  tconv_k<<<dim3(24, 4, 8), 256, 0, stream>>>(Wke, WkeT, 256, 1536, 393216, 393216);

  // fp32 routing path (top-k selection must not see bf16 noise)
  wfuse_k<<<32, 256, 0, stream>>>(Wq, Wgt, Wf);
  logits_k<<<2048, 256, 0, stream>>>(hs, Wf, lg);
  routing_k<<<64, 256, 0, stream>>>(lg, rwB);

  // merged q|k|g projection (one dispatch, N=8192) + separate v projection
  gemm_bt<0><<<dim3(64, 16, 1), 256, 0, stream>>>(hs_bf, WcatT, qkg, 2048, 2048, 2048, 8192, 0, 0);
  gemm_bt<0><<<dim3(32, 16, 1), 256, 0, stream>>>(hs_bf, WvT, vb, 2048, 2048, 2048, 4096, 0, 0);
  tv_k<<<dim3(16, 8, 16), 256, 0, stream>>>(vb, Vt);

  // per-head expert expansions -> qe/ke [r][b][h][t][256]  (qeB overlays region A: all dead)
  gemm_bt<1><<<dim3(12, 16, 8), 256, 0, stream>>>(qkg, WqeT, qeB, 256, 8192, 256, 0, 256, 393216);
  gemm_bt<1><<<dim3(12, 16, 8), 256, 0, stream>>>(qkg + 2048, WkeT, keB, 256, 8192, 256, 0, 256, 393216);

  // fused attention over experts + combine + SiLU gate (ocB overlays vb: dead after tv_k)
  attn_k<<<256, 256, 0, stream>>>(qeB, keB, Vt, rwB, qkg + 4096, ocB);

  // output projection (fp32 out)
  gemm_bt<2><<<dim3(16, 16, 1), 256, 0, stream>>>(ocB, WoT, out, 4096, 4096, 4096, 2048, 0, 0);
}

// Round 7
// 723.341 us; speedup vs baseline: 1.1856x; 1.1856x over previous
//
#include <hip/hip_runtime.h>
#include <hip/hip_bf16.h>
#include <cstdint>
#include <cstddef>

// H=8 D=256 R=6 S=2 K=2 EV=2, HID=2048, DV=512, b=2, t=1024
typedef __bf16 bf16_t;
typedef __bf16 bf16x8 __attribute__((ext_vector_type(8)));
typedef float f32x4 __attribute__((ext_vector_type(4)));

typedef __attribute__((address_space(3))) unsigned int lds_uint_t;
typedef __attribute__((address_space(1))) unsigned int glob_uint_t;

__device__ __forceinline__ void gload16(const void* g, void* l) {
  __builtin_amdgcn_global_load_lds((const glob_uint_t*)g, (lds_uint_t*)l, 16, 0, 0);
}

__device__ __forceinline__ f32x4 mfma16(bf16x8 a, bf16x8 b, f32x4 c) {
  return __builtin_amdgcn_mfma_f32_16x16x32_bf16(a, b, c, 0, 0, 0);
}

// ---------------- flat f32 -> bf16 ----------------
__global__ __launch_bounds__(256) void conv_bf16_k(const float* __restrict__ in,
                                                   bf16_t* __restrict__ out, int n8) {
  int i = blockIdx.x * 256 + threadIdx.x;
  if (i >= n8) return;
  f32x4 a = *(const f32x4*)(in + (size_t)i * 8);
  f32x4 b = *(const f32x4*)(in + (size_t)i * 8 + 4);
  bf16x8 o;
  o[0] = (bf16_t)a[0]; o[1] = (bf16_t)a[1]; o[2] = (bf16_t)a[2]; o[3] = (bf16_t)a[3];
  o[4] = (bf16_t)b[0]; o[5] = (bf16_t)b[1]; o[6] = (bf16_t)b[2]; o[7] = (bf16_t)b[3];
  *(bf16x8*)(out + (size_t)i * 8) = o;
}

// ---------------- transpose + convert: in f32 [R][C] -> out bf16 [C][R] ----------------
__global__ __launch_bounds__(256) void tconv_k(const float* __restrict__ in, bf16_t* __restrict__ out,
                                               int R, int C, size_t inZ, size_t outZ) {
  __shared__ __align__(16) bf16_t t[64 * 72];
  in += (size_t)blockIdx.z * inZ;
  out += (size_t)blockIdx.z * outZ;
  const int c0 = blockIdx.x * 64, r0 = blockIdx.y * 64;
  const int tid = threadIdx.x;
#pragma unroll
  for (int it = 0; it < 4; it++) {
    int c = tid + it * 256;           // 1024 chunks of 4 floats (64 rows x 16)
    int row = c >> 4, ch = c & 15;
    f32x4 v = *(const f32x4*)(in + (size_t)(r0 + row) * C + c0 + ch * 4);
#pragma unroll
    for (int j = 0; j < 4; j++) t[(ch * 4 + j) * 72 + row] = (bf16_t)v[j];
  }
  __syncthreads();
#pragma unroll
  for (int it = 0; it < 2; it++) {
    int c = tid + it * 256;           // 512 chunks of 8 bf16 (64 out-rows x 8)
    int oc = c >> 3, ch = c & 7;
    bf16x8 v = *(const bf16x8*)(t + oc * 72 + ch * 8);
    *(bf16x8*)(out + (size_t)(c0 + oc) * R + r0 + ch * 8) = v;
  }
}

// ---------------- transpose V: qkg cols [8192,12288) bf16 -> Vt [b][h][512][1024] ----------------
__global__ __launch_bounds__(256) void tv_k(const bf16_t* __restrict__ v, bf16_t* __restrict__ Vt) {
  __shared__ __align__(16) bf16_t t[64 * 72];
  const int tt0 = blockIdx.x * 64;
  const int dv0 = blockIdx.y * 64;
  const int bh = blockIdx.z;
  const int b = bh >> 3, h = bh & 7;
  const int tid = threadIdx.x;
  const bf16_t* src = v + (size_t)(b * 1024 + tt0) * 12288 + 8192 + h * 512 + dv0;
#pragma unroll
  for (int it = 0; it < 2; it++) {
    int c = tid + it * 256;           // 64 t-rows x 8 chunks
    int row = c >> 3, ch = c & 7;
    bf16x8 x = *(const bf16x8*)(src + (size_t)row * 12288 + ch * 8);
#pragma unroll
    for (int j = 0; j < 8; j++) t[(ch * 8 + j) * 72 + row] = x[j];
  }
  __syncthreads();
  bf16_t* dst = Vt + (size_t)bh * 524288 + (size_t)dv0 * 1024 + tt0;
#pragma unroll
  for (int it = 0; it < 2; it++) {
    int c = tid + it * 256;           // 64 dv-rows x 8 chunks
    int od = c >> 3, ch = c & 7;
    bf16x8 x = *(const bf16x8*)(t + od * 72 + ch * 8);
    *(bf16x8*)(dst + (size_t)od * 1024 + ch * 8) = x;
  }
}

// ---------------- Wfused[kk][h*4+n] = sum_d Wq[kk][h*256+d] * Wgate[d][n] (fp32) ----------------
__global__ __launch_bounds__(256) void wfuse_k(const float* __restrict__ Wq, const float* __restrict__ Wgate,
                                               float* __restrict__ Wf) {
  __shared__ float wg[1024];
  const int tid = threadIdx.x;
  for (int i = tid; i < 1024; i += 256) wg[i] = Wgate[i];
  __syncthreads();
  const int kk = blockIdx.x * 64 + (tid & 63);
  const int oid = tid >> 6;  // 0..3 -> outputs oid*8..+7
  float acc[8] = {0, 0, 0, 0, 0, 0, 0, 0};
  const float* wr = Wq + (size_t)kk * 2048;
#pragma unroll
  for (int half = 0; half < 2; half++) {
    const int h = oid * 2 + half;
    const float* seg = wr + h * 256;
    for (int d = 0; d < 256; d += 4) {
      f32x4 q4 = *(const f32x4*)(seg + d);
#pragma unroll
      for (int n = 0; n < 4; n++) {
        acc[half * 4 + n] += q4[0] * wg[(d + 0) * 4 + n] + q4[1] * wg[(d + 1) * 4 + n] +
                             q4[2] * wg[(d + 2) * 4 + n] + q4[3] * wg[(d + 3) * 4 + n];
      }
    }
  }
#pragma unroll
  for (int jj = 0; jj < 8; jj++) Wf[(size_t)kk * 32 + oid * 8 + jj] = acc[jj];
}

// ---------------- logits[bt][32] = hs[bt] @ Wfused (fp32) ----------------
__global__ __launch_bounds__(256) void logits_k(const float* __restrict__ hs, const float* __restrict__ Wf,
                                                float* __restrict__ lg) {
  __shared__ __align__(16) float hrow[2048];
  __shared__ float red[8][32];
  const int bt = blockIdx.x;
  const int tid = threadIdx.x;
  const float* src = hs + (size_t)bt * 2048;
  for (int i = tid; i < 512; i += 256) *(f32x4*)&hrow[i * 4] = *(const f32x4*)(src + i * 4);
  __syncthreads();
  const int j = tid & 31, part = tid >> 5;
  float acc = 0.f;
  for (int kk = part * 256; kk < part * 256 + 256; kk++) acc += hrow[kk] * Wf[(size_t)kk * 32 + j];
  red[part][j] = acc;
  __syncthreads();
  if (tid < 32) {
    float s = 0.f;
#pragma unroll
    for (int p = 0; p < 8; p++) s += red[p][tid];
    lg[(size_t)bt * 32 + tid] = s;
  }
}

// ---------------- routing: softmax over 4, top-2, weights -> rw[r][b][h][t] (fp32) ----------------
__global__ __launch_bounds__(256) void routing_k(const float* __restrict__ lg, float* __restrict__ rw) {
  int gid = blockIdx.x * 256 + threadIdx.x;
  if (gid >= 16384) return;
  const int h = gid >> 11;
  const int bt = gid & 2047;
  const int b = bt >> 10, tt = bt & 1023;
  f32x4 l = *(const f32x4*)(lg + (size_t)bt * 32 + h * 4);
  float mx = fmaxf(fmaxf(l[0], l[1]), fmaxf(l[2], l[3]));
  float e0 = __expf(l[0] - mx), e1 = __expf(l[1] - mx), e2 = __expf(l[2] - mx), e3 = __expf(l[3] - mx);
  float den = e0 + e1 + e2 + e3;
  float s[4] = {e0 / den, e1 / den, e2 / den, e3 / den};
  int i1 = 0;
#pragma unroll
  for (int i = 1; i < 4; i++) if (s[i] > s[i1]) i1 = i;
  int i2 = (i1 == 0) ? 1 : 0;
#pragma unroll
  for (int i = 0; i < 4; i++) if (i != i1 && s[i] > s[i2]) i2 = i;
  float sw = s[i1] + s[i2];
  float w1 = s[i1] / sw, w2 = s[i2] / sw;
  float tot = 1.0f + w1 + w2;
  float o[6] = {0.5f / tot, 0.5f / tot, 0.f, 0.f, 0.f, 0.f};
  o[2 + i1] = w1 / tot;
  o[2 + i2] = w2 / tot;
#pragma unroll
  for (int r = 0; r < 6; r++) rw[(size_t)((r * 2 + b) * 8 + h) * 1024 + tt] = o[r];
}

// ---------------- bf16 GEMM, 128x128 tile, BK=64 (A row-major, B stored transposed [N][K]) ----------
// MODE 0: C bf16 [M][ldc]; MODE 2: C f32.
template <int MODE>
__global__ __launch_bounds__(256) void gemm_bt(const bf16_t* __restrict__ A, const bf16_t* __restrict__ B,
                                               void* __restrict__ Cp, int K, int lda, int ldb, int ldc) {
  __shared__ __align__(16) bf16_t lsA[128 * 64];
  __shared__ __align__(16) bf16_t lsB[128 * 64];
  const int tid = threadIdx.x;
  const int lane = tid & 63, wv = tid >> 6;
  const int lrow = lane & 15, lgrp = lane >> 4;
  const int wr = wv >> 1, wc = wv & 1;
  const int bn = blockIdx.x * 128, bm = blockIdx.y * 128;

  f32x4 zero = {0.f, 0.f, 0.f, 0.f};
  f32x4 acc[4][4];
#pragma unroll
  for (int i = 0; i < 4; i++)
#pragma unroll
    for (int j = 0; j < 4; j++) acc[i][j] = zero;

  for (int k0 = 0; k0 < K; k0 += 64) {
    __syncthreads();
#pragma unroll
    for (int it = 0; it < 4; it++) {
      int c = tid + it * 256;
      int row = c >> 3, coff = (c & 7) * 16;
      gload16((const char*)A + ((size_t)(bm + row) * lda + k0) * 2 + coff, (char*)lsA + row * 128 + coff);
      gload16((const char*)B + ((size_t)(bn + row) * ldb + k0) * 2 + coff, (char*)lsB + row * 128 + coff);
    }
    __syncthreads();
#pragma unroll
    for (int kk = 0; kk < 2; kk++) {
      bf16x8 af[4], bfr[4];
#pragma unroll
      for (int m4 = 0; m4 < 4; m4++)
        af[m4] = *(const bf16x8*)((const char*)lsA + (wr * 64 + m4 * 16 + lrow) * 128 + kk * 64 + lgrp * 16);
#pragma unroll
      for (int n4 = 0; n4 < 4; n4++)
        bfr[n4] = *(const bf16x8*)((const char*)lsB + (wc * 64 + n4 * 16 + lrow) * 128 + kk * 64 + lgrp * 16);
#pragma unroll
      for (int m4 = 0; m4 < 4; m4++)
#pragma unroll
        for (int n4 = 0; n4 < 4; n4++) acc[m4][n4] = mfma16(af[m4], bfr[n4], acc[m4][n4]);
    }
  }
#pragma unroll
  for (int m4 = 0; m4 < 4; m4++) {
#pragma unroll
    for (int i = 0; i < 4; i++) {
      const int row = bm + wr * 64 + m4 * 16 + lgrp * 4 + i;
#pragma unroll
      for (int n4 = 0; n4 < 4; n4++) {
        const int col = bn + wc * 64 + n4 * 16 + lrow;
        float v = acc[m4][n4][i];
        if constexpr (MODE == 0) {
          ((bf16_t*)Cp)[(size_t)row * ldc + col] = (bf16_t)v;
        } else {
          ((float*)Cp)[(size_t)row * ldc + col] = v;
        }
      }
    }
  }
}

// ---------------- merged expert-expansion GEMM: z in [0,16): sel=z>>3 (0=q,1=k), head=z&7 -----------
// A = qkg + sel*2048 + head*256 (lda 12288), B = W{q,k}eT[head] ([1536][256]), K=256.
// C scattered into {qe,ke}[r][b][head][t][256].
__global__ __launch_bounds__(256) void gemm_exp(const bf16_t* __restrict__ qkg, const bf16_t* __restrict__ Wqe,
                                                const bf16_t* __restrict__ Wke, bf16_t* __restrict__ qeB,
                                                bf16_t* __restrict__ keB) {
  __shared__ __align__(16) bf16_t lsA[128 * 64];
  __shared__ __align__(16) bf16_t lsB[128 * 64];
  const int tid = threadIdx.x;
  const int lane = tid & 63, wv = tid >> 6;
  const int lrow = lane & 15, lgrp = lane >> 4;
  const int wr = wv >> 1, wc = wv & 1;
  const int bn = blockIdx.x * 128, bm = blockIdx.y * 128;
  const int z = blockIdx.z;
  const int sel = z >> 3, hh = z & 7;
  const bf16_t* A = qkg + sel * 2048 + hh * 256;
  const bf16_t* B = (sel ? Wke : Wqe) + (size_t)hh * 393216;
  bf16_t* C = sel ? keB : qeB;

  f32x4 zero = {0.f, 0.f, 0.f, 0.f};
  f32x4 acc[4][4];
#pragma unroll
  for (int i = 0; i < 4; i++)
#pragma unroll
    for (int j = 0; j < 4; j++) acc[i][j] = zero;

  for (int k0 = 0; k0 < 256; k0 += 64) {
    __syncthreads();
#pragma unroll
    for (int it = 0; it < 4; it++) {
      int c = tid + it * 256;
      int row = c >> 3, coff = (c & 7) * 16;
      gload16((const char*)A + ((size_t)(bm + row) * 12288 + k0) * 2 + coff, (char*)lsA + row * 128 + coff);
      gload16((const char*)B + ((size_t)(bn + row) * 256 + k0) * 2 + coff, (char*)lsB + row * 128 + coff);
    }
    __syncthreads();
#pragma unroll
    for (int kk = 0; kk < 2; kk++) {
      bf16x8 af[4], bfr[4];
#pragma unroll
      for (int m4 = 0; m4 < 4; m4++)
        af[m4] = *(const bf16x8*)((const char*)lsA + (wr * 64 + m4 * 16 + lrow) * 128 + kk * 64 + lgrp * 16);
#pragma unroll
      for (int n4 = 0; n4 < 4; n4++)
        bfr[n4] = *(const bf16x8*)((const char*)lsB + (wc * 64 + n4 * 16 + lrow) * 128 + kk * 64 + lgrp * 16);
#pragma unroll
      for (int m4 = 0; m4 < 4; m4++)
#pragma unroll
        for (int n4 = 0; n4 < 4; n4++) acc[m4][n4] = mfma16(af[m4], bfr[n4], acc[m4][n4]);
    }
  }
#pragma unroll
  for (int m4 = 0; m4 < 4; m4++) {
#pragma unroll
    for (int i = 0; i < 4; i++) {
      const int row = bm + wr * 64 + m4 * 16 + lgrp * 4 + i;
      const int bb = row >> 10, tt = row & 1023;
#pragma unroll
      for (int n4 = 0; n4 < 4; n4++) {
        const int col = bn + wc * 64 + n4 * 16 + lrow;
        const int rr = col >> 8, dd = col & 255;
        C[((size_t)((rr * 2 + bb) * 8 + hh) * 1024 + tt) * 256 + dd] = (bf16_t)acc[m4][n4][i];
      }
    }
  }
}

// ---------------- fused masked attention over all 6 experts + combine + SiLU gate ----------------
// 512 linear blocks, XCD-swizzled. 256 threads (4 waves x 16 q-rows), 2 blocks/CU.
// Fixed-M softmax; masked key -> exp(0)=1 in denom, 0 in PV.
__global__ __launch_bounds__(256, 2) void attn_k(const bf16_t* __restrict__ qe, const bf16_t* __restrict__ ke,
                                                 const bf16_t* __restrict__ Vt, const float* __restrict__ rw,
                                                 const bf16_t* __restrict__ g, bf16_t* __restrict__ oc) {
  __shared__ __align__(16) bf16_t ldsK[2][32 * 256];   // [buf][row 512B], swizzled: off ^= (row&7)<<4
  __shared__ __align__(16) bf16_t ldsV[2][256 * 32];   // [buf][row 64B],  swizzled: off ^= ((row>>1)&3)<<4
  __shared__ __align__(16) bf16_t ldsP[4 * 16 * 40];   // per-wave 16 q x 32 keys, row-permuted

  // XCD-aware swizzle (T1): each XCD owns 64 consecutive logical blocks -> same-bh co-location.
  const int f = (blockIdx.x & 7) * 64 + (blockIdx.x >> 3);
  const int qt = f & 15, dvh = (f >> 4) & 1, bh = f >> 5;

  const int tid = threadIdx.x;
  const int wv = tid >> 6, lane = tid & 63;
  const int lrow = lane & 15, lgrp = lane >> 4;
  const int b = bh >> 3, h = bh & 7;
  const int qw = qt * 64 + wv * 16;

  const char* vbase = (const char*)Vt + ((size_t)bh * 524288 + (size_t)dvh * 262144) * 2;

  auto issue_tile = [&](int rr, int kt, int buf) {
    const char* kb = (const char*)ke + ((size_t)((rr * 2 + b) * 8 + h) * 262144 + (size_t)kt * 8192) * 2;
    char* lk = (char*)ldsK[buf];
#pragma unroll
    for (int it = 0; it < 4; it++) {
      int p = (wv * 4 + it) * 1024 + (lane << 4);
      int row = p >> 9, off = p & 511;
      gload16(kb + (size_t)row * 512 + (off ^ ((row & 7) << 4)), lk + p);
    }
    const char* vb = vbase + kt * 64;
    char* lv = (char*)ldsV[buf];
#pragma unroll
    for (int it = 0; it < 4; it++) {
      int p = (wv * 4 + it) * 1024 + (lane << 4);
      int row = p >> 6, off = p & 63;
      gload16(vb + (size_t)row * 2048 + (off ^ (((row >> 1) & 3) << 4)), lv + p);
    }
  };

  f32x4 zero = {0.f, 0.f, 0.f, 0.f};
  f32x4 Otot[16];
#pragma unroll
  for (int n = 0; n < 16; n++) Otot[n] = zero;

  int cur = 0;
  issue_tile(0, 0, 0);

  for (int r = 0; r < 6; r++) {
    const size_t rbh = (size_t)((r * 2 + b) * 8 + h);
    const bf16_t* qbase = qe + rbh * 262144;
    const float* rwb = rw + rbh * 1024;

    bf16x8 qf[8];
#pragma unroll
    for (int c = 0; c < 8; c++)
      qf[c] = *(const bf16x8*)(qbase + (size_t)(qw + lrow) * 256 + c * 32 + lgrp * 8);
    float rwq[4];
#pragma unroll
    for (int i = 0; i < 4; i++) rwq[i] = rwb[qw + lgrp * 4 + i];

    float Lp[4] = {0.f, 0.f, 0.f, 0.f};   // per-lane partial denominators
    f32x4 accO[16];
#pragma unroll
    for (int n = 0; n < 16; n++) accO[n] = zero;

    for (int kt = 0; kt < 32; kt++) {
      asm volatile("s_waitcnt vmcnt(0) lgkmcnt(0)" ::: "memory");
      __syncthreads();
      // issue next tile into the other buffer; latency hides under this tile's compute
      {
        int nr = r + ((kt == 31) ? 1 : 0);
        int nkt = (kt + 1) & 31;
        if (nr < 6) issue_tile(nr, nkt, cur ^ 1);
      }
      const char* lK = (const char*)ldsK[cur];
      const char* lV = (const char*)ldsV[cur];
      const float* rwk = rwb + kt * 32;
      float mk0 = rwk[lrow], mk1 = rwk[16 + lrow];

      // S = Q K^T (two 16-key column blocks), swizzled reads
      f32x4 sac0 = zero, sac1 = zero;
      __builtin_amdgcn_s_setprio(1);
#pragma unroll
      for (int c = 0; c < 8; c++) {
        int col = (c * 64 + lgrp * 16) ^ ((lrow & 7) << 4);
        bf16x8 k0 = *(const bf16x8*)(lK + (size_t)lrow * 512 + col);
        bf16x8 k1 = *(const bf16x8*)(lK + (size_t)(16 + lrow) * 512 + col);
        sac0 = mfma16(qf[c], k0, sac0);
        sac1 = mfma16(qf[c], k1, sac1);
      }
      __builtin_amdgcn_s_setprio(0);
      // fixed-M softmax; masked key: 1 in denom, 0 in PV; P row q stored at physical (q&3)*4+(q>>2)
      bf16_t* pb = ldsP + wv * 640;
#pragma unroll
      for (int i = 0; i < 4; i++) {
        float e0 = __expf(sac0[i] * 0.0625f);
        float e1 = __expf(sac1[i] * 0.0625f);
        pb[(i * 4 + lgrp) * 40 + lrow] = (bf16_t)((mk0 != 0.f) ? e0 : 0.f);
        pb[(i * 4 + lgrp) * 40 + 16 + lrow] = (bf16_t)((mk1 != 0.f) ? e1 : 0.f);
        Lp[i] += ((mk0 != 0.f) ? e0 : 1.f) + ((mk1 != 0.f) ? e1 : 1.f);
      }
      bf16x8 pa = *(const bf16x8*)(pb + ((lrow & 3) * 4 + (lrow >> 2)) * 40 + lgrp * 8);
      __builtin_amdgcn_s_setprio(1);
#pragma unroll
      for (int n = 0; n < 16; n++) {
        int row = n * 16 + lrow;
        int col = (lgrp * 16) ^ (((row >> 1) & 3) << 4);
        bf16x8 vf = *(const bf16x8*)(lV + (size_t)row * 64 + col);
        accO[n] = mfma16(pa, vf, accO[n]);
      }
      __builtin_amdgcn_s_setprio(0);
      cur ^= 1;
    }  // kt
    // reduce per-lane denominators across the 16-lane row group (once per r)
#pragma unroll
    for (int i = 0; i < 4; i++) {
      float v = Lp[i];
      v += __shfl_xor(v, 1, 16);
      v += __shfl_xor(v, 2, 16);
      v += __shfl_xor(v, 4, 16);
      v += __shfl_xor(v, 8, 16);
      float inv = rwq[i] / v;
#pragma unroll
      for (int n = 0; n < 16; n++) Otot[n][i] += accO[n][i] * inv;
    }
  }  // r

  // epilogue: o * silu(g) -> O_comb bf16 (g = qkg cols [4096,8192), row stride 12288)
#pragma unroll
  for (int i = 0; i < 4; i++) {
    const size_t grow = ((size_t)(b * 1024 + qw + lgrp * 4 + i)) * 12288 + 4096 + h * 512 + dvh * 256;
    const size_t orow = ((size_t)(b * 1024 + qw + lgrp * 4 + i)) * 4096 + h * 512 + dvh * 256;
#pragma unroll
    for (int n = 0; n < 16; n++) {
      float gv = (float)g[grow + n * 16 + lrow];
      float sg = gv / (1.f + __expf(-gv));
      oc[orow + n * 16 + lrow] = (bf16_t)(Otot[n][i] * sg);
    }
  }
}

// =====================================================================================
extern "C" void kernel_launch(void* const* d_in, const int* in_sizes, int n_in,
                              void* d_out, int out_size, void* d_ws, size_t ws_size,
                              hipStream_t stream) {
  const float* hs  = (const float*)d_in[0];
  const float* Wq  = (const float*)d_in[1];
  const float* Wk  = (const float*)d_in[2];
  const float* Wv  = (const float*)d_in[3];
  const float* Wqe = (const float*)d_in[4];
  const float* Wke = (const float*)d_in[5];
  const float* Wgt = (const float*)d_in[6];
  const float* Wg  = (const float*)d_in[7];
  const float* Wo  = (const float*)d_in[8];
  float* out = (float*)d_out;

  // Liveness-aware workspace layout; peak footprint ~214 MB.
  const size_t MB = 1024 * 1024;
  char* w = (char*)d_ws;
  bf16_t* hs_bf = (bf16_t*)(w + 0 * MB);    // 8MB, dead after mega-proj
  bf16_t* WcatT = (bf16_t*)(w + 8 * MB);    // 48MB: WqT|WkT|WgT|WvT rows (12288 x 2048), dead after proj
  bf16_t* qeB   = (bf16_t*)(w + 0 * MB);    // 48MB, written AFTER proj (overlays hs_bf+WcatT)
  bf16_t* WoT   = (bf16_t*)(w + 56 * MB);   // 16MB, persistent until out-proj
  bf16_t* WqeT  = (bf16_t*)(w + 72 * MB);   // 6MB
  bf16_t* WkeT  = (bf16_t*)(w + 78 * MB);   // 6MB
  bf16_t* qkg   = (bf16_t*)(w + 84 * MB);   // 48MB: [2048][12288] = q|k|g|v merged proj output
  bf16_t* Vt    = (bf16_t*)(w + 132 * MB);  // 16MB
  bf16_t* keB   = (bf16_t*)(w + 148 * MB);  // 48MB
  bf16_t* ocB   = (bf16_t*)(w + 196 * MB);  // 16MB
  float*  Wf    = (float*)(w + 212 * MB);             // 256KB
  float*  lg    = (float*)(w + 212 * MB + 262144);    // 256KB
  float*  rwB   = (float*)(w + 212 * MB + 524288);    // 384KB
  (void)ws_size; (void)in_sizes; (void)n_in; (void)out_size;

  // conversions / transposes
  conv_bf16_k<<<2048, 256, 0, stream>>>(hs, hs_bf, 524288);
  tconv_k<<<dim3(32, 32, 1), 256, 0, stream>>>(Wq, WcatT, 2048, 2048, 0, 0);
  tconv_k<<<dim3(32, 32, 1), 256, 0, stream>>>(Wk, WcatT + 2048 * 2048, 2048, 2048, 0, 0);
  tconv_k<<<dim3(64, 32, 1), 256, 0, stream>>>(Wg, WcatT + 4096 * 2048, 2048, 4096, 0, 0);
  tconv_k<<<dim3(64, 32, 1), 256, 0, stream>>>(Wv, WcatT + 8192 * 2048, 2048, 4096, 0, 0);
  tconv_k<<<dim3(32, 64, 1), 256, 0, stream>>>(Wo, WoT, 4096, 2048, 0, 0);
  tconv_k<<<dim3(24, 4, 8), 256, 0, stream>>>(Wqe, WqeT, 256, 1536, 393216, 393216);
  tconv_k<<<dim3(24, 4, 8), 256, 0, stream>>>(Wke, WkeT, 256, 1536, 393216, 393216);

  // fp32 routing path (top-k selection must not see bf16 noise)
  wfuse_k<<<32, 256, 0, stream>>>(Wq, Wgt, Wf);
  logits_k<<<2048, 256, 0, stream>>>(hs, Wf, lg);
  routing_k<<<64, 256, 0, stream>>>(lg, rwB);

  // single mega projection q|k|g|v (N=12288)
  gemm_bt<0><<<dim3(96, 16, 1), 256, 0, stream>>>(hs_bf, WcatT, qkg, 2048, 2048, 2048, 12288);
  tv_k<<<dim3(16, 8, 16), 256, 0, stream>>>(qkg, Vt);

  // merged per-head expert expansions -> qe/ke [r][b][h][t][256]
  gemm_exp<<<dim3(12, 16, 16), 256, 0, stream>>>(qkg, WqeT, WkeT, qeB, keB);

  // fused attention over experts + combine + SiLU gate
  attn_k<<<512, 256, 0, stream>>>(qeB, keB, Vt, rwB, qkg, ocB);

  // output projection (fp32 out)
  gemm_bt<2><<<dim3(16, 16, 1), 256, 0, stream>>>(ocB, WoT, out, 4096, 4096, 4096, 2048);
}